// Round 23
// baseline (116.090 us; speedup 1.0000x reference)
//
#include <hip/hip_runtime.h>
#include <hip/hip_bf16.h>
#include <stdint.h>

// Problem constants
#define MB 8192     // batch (rows and cols of sim)
#define KD 256      // embedding dim
#define BM 128      // rows per block (4 waves x 32 rows)
#define BN 64       // cols per chunk
#define NSPLIT 8    // column slabs (512 blocks: proven-good L2 behavior)
#define SLAB (MB / NSPLIT)   // 1024 cols per slab
#define NCHUNK (SLAB / BN)   // 16 chunks per slab
#define COFF 104.0f          // fixed exp offset (overflow/underflow-safe)
#define LOG2E 1.44269504088896340736f

typedef __attribute__((ext_vector_type(8))) short bf16x8;
typedef __attribute__((ext_vector_type(4))) float f32x4;

__device__ __forceinline__ unsigned short f2bf(float x) {
  union { float f; uint32_t u; } v; v.f = x;
  uint32_t r = v.u + 0x7fffu + ((v.u >> 16) & 1u);   // RNE
  return (unsigned short)(r >> 16);
}

__device__ __forceinline__ float fast_exp2(float x) {
#if __has_builtin(__builtin_amdgcn_exp2f)
  return __builtin_amdgcn_exp2f(x);
#else
  return exp2f(x);
#endif
}

// async global->LDS DMA, 16B per lane, LDS dest = wave-uniform base + lane*16
#define GLOAD_LDS16(g, l)                                                      \
  __builtin_amdgcn_global_load_lds(                                            \
      (const __attribute__((address_space(1))) void*)(g),                      \
      (__attribute__((address_space(3))) void*)(l), 16, 0, 0)

// ---- prep: fp32->bf16 for A,B + pos_sim + b2 + zero ps/cnt/out ----
__global__ __launch_bounds__(256) void prep_kernel(
    const float* __restrict__ A, const float* __restrict__ B,
    const float* __restrict__ q,
    unsigned short* __restrict__ Abf, unsigned short* __restrict__ Bbf,
    float* __restrict__ pos, float* __restrict__ b2,
    float* __restrict__ ps, float* __restrict__ cnt,
    float* __restrict__ out) {
  int t = blockIdx.x * 256 + threadIdx.x;        // 524288 threads, 1 float4 each
  const float4 a = ((const float4*)A)[t];
  const float4 b = ((const float4*)B)[t];
  ushort4 oa, ob;
  oa.x = f2bf(a.x); oa.y = f2bf(a.y); oa.z = f2bf(a.z); oa.w = f2bf(a.w);
  ob.x = f2bf(b.x); ob.y = f2bf(b.y); ob.z = f2bf(b.z); ob.w = f2bf(b.w);
  ((ushort4*)Abf)[t] = oa;
  ((ushort4*)Bbf)[t] = ob;
  // pos_sim: wave (t>>6) == row, 64 lanes cover KD/4 float4 chunks
  float d = a.x * b.x + a.y * b.y + a.z * b.z + a.w * b.w;
  #pragma unroll
  for (int off = 32; off; off >>= 1) d += __shfl_down(d, off, 64);
  if ((threadIdx.x & 63) == 0) pos[t >> 6] = d;
  // per-row setup: b2 = -(log2 q + C*log2e), zero accumulators
  if (t < MB) {
    b2[t] = -(log2f(q[t]) + COFF * LOG2E);
    ps[t] = 0.0f;
    cnt[t] = 0.0f;
    if (t == 0) out[0] = 0.0f;
  }
}

// ---- fused GEMM + masked fixed-offset exp-sum + miss count ----
// R22 champion structure (counted-vmcnt 2-phase, 53.4us), VALU-polished:
//  - packed {id, b2} int2 LDS table: 1 ds_read_b64 per (ct,chunk) (was 2 reads)
//  - miss-mask epilogue: m = (idj!=idr); srun = fmac(e, m); crun += m
//    (4 VALU/elem, was 5; crun now counts MISSES -> finalize nm = cnt directly)
__global__ __launch_bounds__(256, 2) void fused_kernel(
    const unsigned short* __restrict__ Abf,
    const unsigned short* __restrict__ Bbf,
    const int* __restrict__ ids,
    const float* __restrict__ b2,
    float* __restrict__ ps, float* __restrict__ cnt) {
  const int slab = blockIdx.y;
  const int tid = threadIdx.x;
  const int wave = tid >> 6;
  const int lane = tid & 63;
  const int quad = lane >> 4;
  const int lpos = lane & 15;
  const int rowbase = blockIdx.x * BM + wave * 32;
  const int colbase = slab * SLAB;

  // Fragment-ordered B staging, DOUBLE buffered: cell c = ((ct*8+kb)*4+quad)*16+lpos
  // holds B[col = ct*16+lpos][k = kb*32+quad*8 .. +8). Linear in c == tid + s8*256,
  // matching global_load_lds's uniform-base+lane*16 dest. Frag reads wave-linear
  // (lane i -> byte 16*i) => conflict-free ds_read_b128.
  __shared__ unsigned short Bs[2][2048 * 8];   // 2 x 32 KB
  __shared__ int2 tab_s[SLAB];                 // 8 KB: {id, b2-bits} per slab col

  // slab tables: 1024 entries, 4 per thread, coalesced 16B loads
  const int4   tiv = ((const int4*)(ids + colbase))[tid];
  const float4 tbv = ((const float4*)(b2 + colbase))[tid];

  // A fragments resident: wave owns rows [rowbase, rowbase+32)
  bf16x8 afrag[2][8];
  #pragma unroll
  for (int rt = 0; rt < 2; ++rt)
    #pragma unroll
    for (int kb = 0; kb < 8; ++kb)
      afrag[rt][kb] = *(const bf16x8*)(Abf + (rowbase + rt * 16 + lpos) * KD + kb * 32 + quad * 8);

  // chunk-invariant staging addresses (advance global side by chunk*BN*KD)
  const unsigned short* gsrc[8];
  int ldso[8];                               // short-offset within one buffer
  #pragma unroll
  for (int s8 = 0; s8 < 8; ++s8) {
    int c = tid + s8 * 256;
    int lp = c & 15, qd = (c >> 4) & 3, kb = (c >> 6) & 7, ct = c >> 9;
    gsrc[s8] = Bbf + (colbase + ct * 16 + lp) * KD + kb * 32 + qd * 8;
    ldso[s8] = c * 8;
  }

#define STAGE(T, BUF)                                                          \
  _Pragma("unroll")                                                            \
  for (int s8 = 0; s8 < 8; ++s8)                                               \
    GLOAD_LDS16(gsrc[s8] + (T) * (BN * KD), &Bs[BUF][0] + ldso[s8]);

  int idr[2][4];
  float srun[2][4];
  float crun[2][4];
  #pragma unroll
  for (int rt = 0; rt < 2; ++rt)
    #pragma unroll
    for (int r = 0; r < 4; ++r) {
      idr[rt][r] = ids[rowbase + rt * 16 + quad * 4 + r];
      srun[rt][r] = 0.0f;
      crun[rt][r] = 0.0f;
    }

  // Prologue: stage chunk 0, park packed slab table in LDS, full drain barrier.
  STAGE(0, 0)
  {
    int2* tw = &tab_s[tid * 4];
    tw[0] = make_int2(tiv.x, __float_as_int(tbv.x));
    tw[1] = make_int2(tiv.y, __float_as_int(tbv.y));
    tw[2] = make_int2(tiv.z, __float_as_int(tbv.z));
    tw[3] = make_int2(tiv.w, __float_as_int(tbv.w));
  }
  __syncthreads();                           // chunk 0 + table ready

  // Counted-vmcnt 2-phase loop. Per wave the ONLY in-loop vmem ops are the
  // 8 DMAs/chunk: after issuing T+1's 8, vmcnt(8) retires exactly T's 8.
  // Raw barriers (no vmcnt(0) drain) + "memory"/sched fences per rule #18.
#define FUSED_BODY(T, CUR)                                                     \
  {                                                                            \
    const int nxt = (T) + 1;                                                   \
    if (nxt < NCHUNK) {                                                        \
      STAGE(nxt, (CUR) ^ 1)                                                    \
      asm volatile("s_waitcnt vmcnt(8)" ::: "memory");                         \
    } else {                                                                   \
      asm volatile("s_waitcnt vmcnt(0)" ::: "memory");                         \
    }                                                                          \
    __builtin_amdgcn_s_barrier();            /* all waves: chunk T visible */  \
    __builtin_amdgcn_sched_barrier(0);                                         \
    _Pragma("unroll")                                                          \
    for (int ct = 0; ct < 4; ++ct) {                                           \
      const int2 tb = tab_s[(T) * BN + ct * 16 + lpos];                        \
      const int idj = tb.x;                                                    \
      const float bj = __int_as_float(tb.y);                                   \
      const unsigned short* bp = &Bs[CUR][0] + (ct * 512 + quad * 16 + lpos) * 8; \
      bf16x8 bfrag[8];                                                         \
      _Pragma("unroll")                                                        \
      for (int kb = 0; kb < 8; ++kb)                                           \
        bfrag[kb] = *(const bf16x8*)(bp + kb * 512);                           \
      _Pragma("unroll")                                                        \
      for (int rt = 0; rt < 2; ++rt) {                                         \
        f32x4 acc = {0.0f, 0.0f, 0.0f, 0.0f};                                  \
        _Pragma("unroll")                                                      \
        for (int kb = 0; kb < 8; ++kb)                                         \
          acc = __builtin_amdgcn_mfma_f32_16x16x32_bf16(afrag[rt][kb], bfrag[kb], acc, 0, 0, 0); \
        _Pragma("unroll")                                                      \
        for (int r = 0; r < 4; ++r) {                                          \
          const float m = (idj != idr[rt][r]) ? 1.0f : 0.0f;                   \
          const float e = fast_exp2(__builtin_fmaf(acc[r], LOG2E, bj));        \
          srun[rt][r] = __builtin_fmaf(e, m, srun[rt][r]);                     \
          crun[rt][r] += m;                                                    \
        }                                                                      \
      }                                                                        \
    }                                                                          \
    asm volatile("" ::: "memory");                                             \
    __builtin_amdgcn_s_barrier();            /* Bs[CUR] reads done: safe to */ \
    __builtin_amdgcn_sched_barrier(0);       /* re-stage into CUR next iter */ \
  }

  for (int t2 = 0; t2 < NCHUNK; t2 += 2) {
    FUSED_BODY(t2, 0)
    FUSED_BODY(t2 + 1, 1)
  }
#undef FUSED_BODY
#undef STAGE

  // sum across the 16 lanes of each quad (the 16 columns of the frag)
  #pragma unroll
  for (int rt = 0; rt < 2; ++rt)
    #pragma unroll
    for (int r = 0; r < 4; ++r) {
      float v = srun[rt][r];
      float c = crun[rt][r];
      #pragma unroll
      for (int off = 1; off < 16; off <<= 1) {
        v += __shfl_xor(v, off, 64);
        c += __shfl_xor(c, off, 64);
      }
      if (lpos == 0) {
        atomicAdd(&ps[rowbase + rt * 16 + quad * 4 + r], v);
        atomicAdd(&cnt[rowbase + rt * 16 + quad * 4 + r], c);
      }
    }
}

// ---- finalize: per-row loss, mean ----
__global__ __launch_bounds__(256) void finalize_kernel(
    const float* __restrict__ ps, const float* __restrict__ pos,
    const float* __restrict__ q, const float* __restrict__ cnt,
    float* __restrict__ out) {
  int i = blockIdx.x * 256 + threadIdx.x;   // 32 blocks -> 8192 threads
  const float s = ps[i];
  const float nm = cnt[i];                  // n_miss accumulated directly
  // log S_i = log(s) + C + log(1-q_i) - log(n_miss)
  const float z = logf(s) + COFF + logf(1.0f - q[i]) - logf(nm);
  const float p = pos[i];
  const float hi = fmaxf(p, z), lo = fminf(p, z);
  float loss = -p + hi + log1pf(__expf(lo - hi));

  #pragma unroll
  for (int off = 32; off; off >>= 1) loss += __shfl_down(loss, off, 64);
  __shared__ float red[4];
  if ((threadIdx.x & 63) == 0) red[threadIdx.x >> 6] = loss;
  __syncthreads();
  if (threadIdx.x == 0) {
    float t = red[0] + red[1] + red[2] + red[3];
    atomicAdd(out, t * (1.0f / (float)MB));
  }
}

extern "C" void kernel_launch(void* const* d_in, const int* in_sizes, int n_in,
                              void* d_out, int out_size, void* d_ws, size_t ws_size,
                              hipStream_t stream) {
  (void)in_sizes; (void)n_in; (void)out_size; (void)ws_size;
  const float* input_emb  = (const float*)d_in[0];
  const float* target_emb = (const float*)d_in[1];
  const int*   target_ids = (const int*)d_in[2];
  const float* q_probas   = (const float*)d_in[3];
  float* out = (float*)d_out;

  char* ws = (char*)d_ws;
  unsigned short* Abf = (unsigned short*)(ws);                    // 4 MB
  unsigned short* Bbf = (unsigned short*)(ws + (4u << 20));       // 4 MB
  float* b2   = (float*)(ws + (8u << 20));                        // 32 KB
  float* pos  = (float*)(ws + (8u << 20) + 32768);                // 32 KB
  float* ps   = (float*)(ws + (8u << 20) + 65536);                // 32 KB
  float* cnt  = (float*)(ws + (8u << 20) + 98304);                // 32 KB

  prep_kernel<<<2048, 256, 0, stream>>>(input_emb, target_emb, q_probas,
                                        Abf, Bbf, pos, b2, ps, cnt, out);
  fused_kernel<<<dim3(MB / BM, NSPLIT), 256, 0, stream>>>(Abf, Bbf, target_ids,
                                                          b2, ps, cnt);
  finalize_kernel<<<32, 256, 0, stream>>>(ps, pos, q_probas, cnt, out);
}